// Round 11
// baseline (3430.570 us; speedup 1.0000x reference)
//
#include <hip/hip_runtime.h>

#define Hdim 200
#define NP   800
#define Tlen 100
#define BT   32          // batch rows per WG -> grid = 256 = 1 WG/CU
#define KB   7           // K blocks of 32 (200 -> 224 padded)
#define HS   232         // padded h row stride (ushorts)
#define NT   50          // 800/16 gate-col tiles
#define THREADS 768      // 12 waves = 3/SIMD exactly (R8 win)
#define CHSTR (NT*64*8)  // ushorts per K-chunk (25600)
#define MATSZ (KB*CHSTR) // 179200 ushorts per packed matrix

// s_waitcnt immediates: vm[3:0]|exp[6:4]|lgkm[11:8]|vm[15:14]
#define WAIT_LGKM0 0xC07F   // lgkmcnt(0)

typedef float f32x4 __attribute__((ext_vector_type(4)));
typedef short s16x8 __attribute__((ext_vector_type(8)));

__device__ __forceinline__ ushort f2bf(float f) {
    unsigned u = __float_as_uint(f);
    return (ushort)((u + 0x7fffu + ((u >> 16) & 1u)) >> 16);   // RTNE
}
__device__ __forceinline__ float bf2f(ushort s) {
    return __uint_as_float(((unsigned)s) << 16);
}
__device__ __forceinline__ float sigmoid_fast(float v) {
    return 1.0f / (1.0f + __expf(-v));
}
__device__ __forceinline__ float tanh_fast(float v) {
    return 2.0f / (1.0f + __expf(-2.0f * v)) - 1.0f;
}
// WG barrier WITHOUT vmcnt drain: LDS visibility needs lgkmcnt(0) only.
// Weight DMAs in flight target wave-private buffers -> safe across barrier.
__device__ __forceinline__ void wg_barrier() {
    asm volatile("" ::: "memory");
    __builtin_amdgcn_s_waitcnt(WAIT_LGKM0);
    __builtin_amdgcn_s_barrier();
    asm volatile("" ::: "memory");
}

// ---- pack 5 recurrent matrices [200][800] fp32 -> bf16 fragment layout ----
// order in d_ws: [U0, W1, U1, W2, U2]  (layout unchanged from R0/R8)
__global__ void pack_weights(const float* __restrict__ U0, const float* __restrict__ W1,
                             const float* __restrict__ U1, const float* __restrict__ W2,
                             const float* __restrict__ U2, ushort* __restrict__ dst) {
    int idx = blockIdx.x * blockDim.x + threadIdx.x;
    if (idx >= 5 * KB * NT * 64) return;
    int lane = idx & 63; int rest = idx >> 6;
    int nt = rest % NT; rest /= NT;
    int kb = rest % KB; int mi = rest / KB;
    const float* src = (mi == 0) ? U0 : (mi == 1) ? W1 : (mi == 2) ? U1 : (mi == 3) ? W2 : U2;
    int np = nt * 16 + (lane & 15);
    int ncol = (np & 3) * Hdim + (np >> 2);          // gate*200 + unit
    int k0 = kb * 32 + (lane >> 4) * 8;
    ushort v[8];
#pragma unroll
    for (int j = 0; j < 8; ++j) {
        int k = k0 + j;
        v[j] = (k < Hdim) ? f2bf(src[k * NP + ncol]) : (ushort)0;
    }
    uint4 o;
    o.x = (unsigned)v[0] | ((unsigned)v[1] << 16);
    o.y = (unsigned)v[2] | ((unsigned)v[3] << 16);
    o.z = (unsigned)v[4] | ((unsigned)v[5] << 16);
    o.w = (unsigned)v[6] | ((unsigned)v[7] << 16);
    ((uint4*)dst)[idx] = o;
}

// CHW async DMAs: one K-chunk's CHW fragment tiles -> wave-private LDS buffer.
template<int CHW>
__device__ __forceinline__ void stage_chunk(const ushort* gp, ushort* dstbuf, int lane) {
#pragma unroll
    for (int mt = 0; mt < CHW; ++mt) {
        __builtin_amdgcn_global_load_lds(
            (const __attribute__((address_space(1))) void*)(gp + (size_t)mt * 512 + lane * 8),
            (__attribute__((address_space(3))) void*)(dstbuf + mt * 512),
            16, 0, 0);
    }
}

__device__ __forceinline__ void unpack4(const ushort* p, float (&o)[4]) {
    uint2 u = *(const uint2*)p;
    o[0] = bf2f((ushort)(u.x));  o[1] = bf2f((ushort)(u.x >> 16));
    o[2] = bf2f((ushort)(u.y));  o[3] = bf2f((ushort)(u.y >> 16));
}

// lane-local cell update (R8 body)
template<int CHW>
__device__ __forceinline__ void gate_phase(f32x4 (&acc)[2][CHW],
                                           float (&creg)[2][CHW],
                                           ushort* __restrict__ hbl,
                                           int lane, int S_w) {
    const int l15 = lane & 15, q = lane >> 4;
#pragma unroll
    for (int nt = 0; nt < 2; ++nt) {
#pragma unroll
        for (int mt = 0; mt < CHW; ++mt) {
            const int u = (S_w + mt) * 4 + q;
            const int n = nt * 16 + l15;
            f32x4 z = acc[nt][mt];
            float iv = sigmoid_fast(z[0]);
            float fv = sigmoid_fast(z[1]);
            float gv = tanh_fast(z[2]);
            float ov = sigmoid_fast(z[3]);
            float c = fv * creg[nt][mt] + iv * gv;
            creg[nt][mt] = c;
            hbl[n * HS + u] = f2bf(ov * tanh_fast(c));
        }
    }
}

// One run of slots [s0, s1): identical per-slot body to the verified R0/R8 kernel
// (vmcnt(CHW) wait -> ds_read frags + bh -> 2*CHW MFMA -> lgkmcnt(0) -> restage).
template<int CHW>
__device__ __forceinline__ void run_slots(int s0, int s1, int t,
        ushort* __restrict__ sl, f32x4 (&acc)[2][CHW],
        const ushort* __restrict__ pk, const uint* gTab, const uint* bhTab,
        const ushort* hbflat, int bhbase, int lane, int& isl) {
#pragma unroll 1
    for (int s = s0; s < s1; ++s) {
        __builtin_amdgcn_s_waitcnt(0x0F70 | CHW);   // vmcnt(CHW): other buffer in flight
        ushort* buf = sl + ((t + s) & 1) * (CHW * 512);
        s16x8 frag[CHW];
#pragma unroll
        for (int mt = 0; mt < CHW; ++mt)
            frag[mt] = *(const s16x8*)(buf + mt * 512 + lane * 8);
        const ushort* bp = hbflat + bhTab[s] + bhbase;
        s16x8 bh0 = *(const s16x8*)bp;
        s16x8 bh1 = *(const s16x8*)(bp + 16 * HS);
#pragma unroll
        for (int mt = 0; mt < CHW; ++mt) {
            acc[0][mt] = __builtin_amdgcn_mfma_f32_16x16x32_bf16(frag[mt], bh0, acc[0][mt], 0, 0, 0);
            acc[1][mt] = __builtin_amdgcn_mfma_f32_16x16x32_bf16(frag[mt], bh1, acc[1][mt], 0, 0, 0);
        }
        __builtin_amdgcn_s_waitcnt(WAIT_LGKM0);  // WAR: frag reads done before restage
        stage_chunk<CHW>(pk + gTab[isl], buf, lane);
        isl = (isl == 34) ? 0 : isl + 1;
    }
}

// Full 100-step loop, templated on the wave's tile count. Both instantiations
// execute an identical barrier sequence (6/step), so divergent wave-uniform
// dispatch below is barrier-safe. NO weight state in VGPRs across barriers:
// R1/R5/R9 proved any such state trips the allocator into the 84-reg spill
// regime (1.9-2.8 GB scratch traffic).
template<int CHW>
__device__ __forceinline__ void time_loop(const int S_w, const int lane,
        const int bhbase, ushort* __restrict__ sl, const ushort* __restrict__ pk,
        const uint* gTab, const uint* bhTab, ushort* __restrict__ hbflat,
        const ushort (&pbwb)[4][NP], const ushort (&xTs)[Tlen][BT]) {
    const int l15 = lane & 15, q = lane >> 4;

    float creg[3][2][CHW];
#pragma unroll
    for (int l = 0; l < 3; ++l)
#pragma unroll
        for (int nt = 0; nt < 2; ++nt)
#pragma unroll
            for (int mt = 0; mt < CHW; ++mt) creg[l][nt][mt] = 0.0f;

    // prologue: issue slots 0,1 (parities 0,1); steady 2*CHW DMAs in flight
    stage_chunk<CHW>(pk + gTab[0], sl, lane);
    stage_chunk<CHW>(pk + gTab[1], sl + CHW * 512, lane);
    int isl = 2;

    for (int t = 0; t < Tlen; ++t) {
        f32x4 acc[2][CHW];

        // ---- layer 0 acc init: b0 + W0^T x_t (bf16 LDS constants) ----
        const float xn0 = bf2f(xTs[t][l15]);
        const float xn1 = bf2f(xTs[t][16 + l15]);
#pragma unroll
        for (int mt = 0; mt < CHW; ++mt) {
            const int row = (S_w + mt) * 16 + q * 4;
            float bb[4], ww[4];
            unpack4(&pbwb[0][row], bb);
            unpack4(&pbwb[3][row], ww);
#pragma unroll
            for (int r = 0; r < 4; ++r) {
                acc[0][mt][r] = fmaf(xn0, ww[r], bb[r]);
                acc[1][mt][r] = fmaf(xn1, ww[r], bb[r]);
            }
        }

        // ---- region A: slots 0..6 (U0 x h0_old) ----
        run_slots<CHW>(0, 7, t, sl, acc, pk, gTab, bhTab, hbflat, bhbase, lane, isl);
        wg_barrier();
        gate_phase<CHW>(acc, creg[0], hbflat + 0 * BT * HS, lane, S_w);
        wg_barrier();

        // ---- layer 1 acc init ----
#pragma unroll
        for (int mt = 0; mt < CHW; ++mt) {
            const int row = (S_w + mt) * 16 + q * 4;
            float bb[4];
            unpack4(&pbwb[1][row], bb);
#pragma unroll
            for (int r = 0; r < 4; ++r) { acc[0][mt][r] = bb[r]; acc[1][mt][r] = bb[r]; }
        }
        // ---- region B: slots 7..20 (U1 x h1_old, W1 x h0_new, rotated mix) ----
        run_slots<CHW>(7, 21, t, sl, acc, pk, gTab, bhTab, hbflat, bhbase, lane, isl);
        wg_barrier();
        gate_phase<CHW>(acc, creg[1], hbflat + 1 * BT * HS, lane, S_w);
        wg_barrier();

        // ---- layer 2 acc init ----
#pragma unroll
        for (int mt = 0; mt < CHW; ++mt) {
            const int row = (S_w + mt) * 16 + q * 4;
            float bb[4];
            unpack4(&pbwb[2][row], bb);
#pragma unroll
            for (int r = 0; r < 4; ++r) { acc[0][mt][r] = bb[r]; acc[1][mt][r] = bb[r]; }
        }
        // ---- region C: slots 21..34 (U2 x h2_old, W2 x h1_new, rotated mix) ----
        run_slots<CHW>(21, 35, t, sl, acc, pk, gTab, bhTab, hbflat, bhbase, lane, isl);
        wg_barrier();
        gate_phase<CHW>(acc, creg[2], hbflat + 2 * BT * HS, lane, S_w);
        wg_barrier();
    }
}

__global__ void __launch_bounds__(THREADS)
lstm3_mfma(const float* __restrict__ x,
           const float* __restrict__ W0, const float* __restrict__ b0,
           const float* __restrict__ b1, const float* __restrict__ b2,
           const float* __restrict__ Wfc, const float* __restrict__ bfc,
           const ushort* __restrict__ packed,
           float* __restrict__ out) {
    __shared__ ushort hb[3][BT][HS];        // h state, bf16 (44.5 KB)
    __shared__ ushort stage[NT * 1024];     // per-wave 2-deep staging (100 KB); head reuses as f32
    __shared__ ushort pbwb[4][NP];          // permuted b0,b1,b2,W0 as bf16 (6.4 KB)
    __shared__ ushort xTs[Tlen][BT];        // x transposed, bf16 (6.4 KB)
    __shared__ uint   gTab[35];             // rotated weight-chunk offsets (ushorts)
    __shared__ uint   bhTab[35];            // matching h-operand offsets (ushorts)

    const int tid = threadIdx.x;
    const int wave = tid >> 6, lane = tid & 63;
    const int bx = blockIdx.x;
    const int bbase = bx * BT;

    for (int i = tid; i < 3 * BT * HS; i += THREADS) ((ushort*)hb)[i] = 0;
    for (int i = tid; i < NP; i += THREADS) {
        int nc = (i & 3) * Hdim + (i >> 2);   // permuted col -> src col
        pbwb[0][i] = f2bf(b0[nc]); pbwb[1][i] = f2bf(b1[nc]);
        pbwb[2][i] = f2bf(b2[nc]); pbwb[3][i] = f2bf(W0[nc]);
    }
    for (int i = tid; i < BT * Tlen; i += THREADS) {
        int m = i / Tlen, tt = i % Tlen;
        xTs[tt][m] = f2bf(x[(size_t)(bbase + m) * Tlen + tt]);
    }
    // per-WG rotated chunk tables: slot s in [0,35) -> weight offset + h offset
    // (identical to the verified R0/R8 tables)
    if (tid < 35) {
        int s = tid; uint goff, bhoff;
        if (s < 7) {                       // layer0: U0, B=h0
            int c = (s + bx) % 7;
            goff = 0u * MATSZ + c * CHSTR;           bhoff = 0u * BT * HS + c * 32;
        } else if (s < 21) {               // layer1: U1 (B=h1) then W1 (B=h0new), rotated
            int c = (s - 7 + bx) % 14;
            if (c < 7) { goff = 2u * MATSZ + c * CHSTR;       bhoff = 1u * BT * HS + c * 32; }
            else       { goff = 1u * MATSZ + (c - 7) * CHSTR; bhoff = 0u * BT * HS + (c - 7) * 32; }
        } else {                           // layer2: U2 (B=h2) then W2 (B=h1new), rotated
            int c = (s - 21 + bx * 5) % 14;
            if (c < 7) { goff = 4u * MATSZ + c * CHSTR;       bhoff = 2u * BT * HS + c * 32; }
            else       { goff = 3u * MATSZ + (c - 7) * CHSTR; bhoff = 1u * BT * HS + (c - 7) * 32; }
        }
        gTab[s] = goff; bhTab[s] = bhoff;
    }
    __syncthreads();

    // Tile split: waves 0,1 own 5 tiles; waves 2..11 own 4 (total 50).
    // Round-robin wave->SIMD: per-SIMD tiles {13,13,12,12} (R8 win).
    const int S_w = (wave < 2) ? wave * 5 : 10 + (wave - 2) * 4;
    const ushort* pk = packed + (size_t)S_w * 512;   // wave's first tile
    ushort* sl = &stage[S_w * 1024];                 // 2 x CHW x 512 ushorts
    ushort* hbflat = &hb[0][0][0];
    const int bhbase = (lane & 15) * HS + (lane >> 4) * 8;

    if (wave < 2) time_loop<5>(S_w, lane, bhbase, sl, pk, gTab, bhTab, hbflat, pbwb, xTs);
    else          time_loop<4>(S_w, lane, bhbase, sl, pk, gTab, bhTab, hbflat, pbwb, xTs);

    __syncthreads();   // full drain (vmcnt0+lgkm0: absorbs wrap DMAs) + h2 visibility

    // ---- dense head, Wfc LDS-tiled: y = tanh(h2 @ Wfc + bfc) ----
    // Untiled head re-read Wfc from L2: 10.2 MB/CU (~66 us serial tail). Tile k
    // in 4 chunks of 50 rows (50x400 f32 = 80 KB) through the now-dead stage
    // buffer: 320 KB/CU global + LDS-rate reads.
    float* wbuf = (float*)stage;
    float4 a4[5];
#pragma unroll
    for (int r = 0; r < 5; ++r) {
        int gidx = tid + r * THREADS;
        if (gidx < BT * 100) a4[r] = *(const float4*)(bfc + (gidx % 100) * 4);
    }
    for (int kc = 0; kc < 4; ++kc) {
        __syncthreads();
        for (int i = tid; i < 50 * 400; i += THREADS)
            wbuf[i] = Wfc[kc * 50 * 400 + i];
        __syncthreads();
#pragma unroll
        for (int r = 0; r < 5; ++r) {
            int gidx = tid + r * THREADS;
            if (gidx < BT * 100) {
                int m = gidx / 100, j4 = (gidx % 100) * 4;
                const ushort* h2 = &hb[2][m][kc * 50];
                float4 s = a4[r];
                for (int k = 0; k < 50; ++k) {
                    float hk = bf2f(h2[k]);
                    float4 w4 = *(const float4*)(wbuf + k * 400 + j4);
                    s.x = fmaf(hk, w4.x, s.x);
                    s.y = fmaf(hk, w4.y, s.y);
                    s.z = fmaf(hk, w4.z, s.z);
                    s.w = fmaf(hk, w4.w, s.w);
                }
                a4[r] = s;
            }
        }
    }
#pragma unroll
    for (int r = 0; r < 5; ++r) {
        int gidx = tid + r * THREADS;
        if (gidx < BT * 100) {
            int m = gidx / 100, j4 = (gidx % 100) * 4;
            float4 o4;
            o4.x = tanh_fast(a4[r].x); o4.y = tanh_fast(a4[r].y);
            o4.z = tanh_fast(a4[r].z); o4.w = tanh_fast(a4[r].w);
            *(float4*)(out + (size_t)(bbase + m) * 400 + j4) = o4;
        }
    }
}

extern "C" void kernel_launch(void* const* d_in, const int* in_sizes, int n_in,
                              void* d_out, int out_size, void* d_ws, size_t ws_size,
                              hipStream_t stream) {
    const float* x   = (const float*)d_in[0];
    const float* W0  = (const float*)d_in[1];
    const float* U0  = (const float*)d_in[2];
    const float* b0  = (const float*)d_in[3];
    const float* W1  = (const float*)d_in[4];
    const float* U1  = (const float*)d_in[5];
    const float* b1  = (const float*)d_in[6];
    const float* W2  = (const float*)d_in[7];
    const float* U2  = (const float*)d_in[8];
    const float* b2  = (const float*)d_in[9];
    const float* Wfc = (const float*)d_in[10];
    const float* bfc = (const float*)d_in[11];
    float* out = (float*)d_out;
    ushort* packed = (ushort*)d_ws;

    const int B = in_sizes[0] / Tlen;   // 8192
    const int pack_threads = 5 * KB * NT * 64;
    pack_weights<<<(pack_threads + 255) / 256, 256, 0, stream>>>(U0, W1, U1, W2, U2, packed);
    lstm3_mfma<<<B / BT, THREADS, 0, stream>>>(x, W0, b0, b1, b2, Wfc, bfc, packed, out);
}

// Round 12
// 2655.796 us; speedup vs baseline: 1.2917x; 1.2917x over previous
//
#include <hip/hip_runtime.h>

#define Hdim 200
#define NP   800
#define Tlen 100
#define BT   32          // batch rows per WG -> grid = 256 = 1 WG/CU
#define KB   7           // K blocks of 32 (200 -> 224 padded)
#define HS   232         // padded h row stride (ushorts)
#define NT   50          // 800/16 gate-col tiles
#define THREADS 768      // 12 waves = 3/SIMD exactly (R8 win)
#define CHSTR (NT*64*8)  // ushorts per K-chunk (25600)
#define MATSZ (KB*CHSTR) // 179200 ushorts per packed matrix

// s_waitcnt immediates: vm[3:0]|exp[6:4]|lgkm[11:8]|vm[15:14]
#define WAIT_LGKM0 0xC07F   // lgkmcnt(0)

typedef float f32x4 __attribute__((ext_vector_type(4)));
typedef short s16x8 __attribute__((ext_vector_type(8)));

__device__ __forceinline__ ushort f2bf(float f) {
    unsigned u = __float_as_uint(f);
    return (ushort)((u + 0x7fffu + ((u >> 16) & 1u)) >> 16);   // RTNE
}
__device__ __forceinline__ float bf2f(ushort s) {
    return __uint_as_float(((unsigned)s) << 16);
}
__device__ __forceinline__ float sigmoid_fast(float v) {
    return 1.0f / (1.0f + __expf(-v));
}
__device__ __forceinline__ float tanh_fast(float v) {
    return 2.0f / (1.0f + __expf(-2.0f * v)) - 1.0f;
}
// WG barrier WITHOUT vmcnt drain: LDS visibility needs lgkmcnt(0) only.
// Weight DMAs in flight target wave-private buffers -> safe across barrier.
__device__ __forceinline__ void wg_barrier() {
    asm volatile("" ::: "memory");
    __builtin_amdgcn_s_waitcnt(WAIT_LGKM0);
    __builtin_amdgcn_s_barrier();
    asm volatile("" ::: "memory");
}

// ---- pack 5 recurrent matrices [200][800] fp32 -> bf16 fragment layout ----
// order in d_ws: [U0, W1, U1, W2, U2]  (tile layout unchanged from R0)
__global__ void pack_weights(const float* __restrict__ U0, const float* __restrict__ W1,
                             const float* __restrict__ U1, const float* __restrict__ W2,
                             const float* __restrict__ U2, ushort* __restrict__ dst) {
    int idx = blockIdx.x * blockDim.x + threadIdx.x;
    if (idx >= 5 * KB * NT * 64) return;
    int lane = idx & 63; int rest = idx >> 6;
    int nt = rest % NT; rest /= NT;
    int kb = rest % KB; int mi = rest / KB;
    const float* src = (mi == 0) ? U0 : (mi == 1) ? W1 : (mi == 2) ? U1 : (mi == 3) ? W2 : U2;
    int np = nt * 16 + (lane & 15);
    int ncol = (np & 3) * Hdim + (np >> 2);          // gate*200 + unit
    int k0 = kb * 32 + (lane >> 4) * 8;
    ushort v[8];
#pragma unroll
    for (int j = 0; j < 8; ++j) {
        int k = k0 + j;
        v[j] = (k < Hdim) ? f2bf(src[k * NP + ncol]) : (ushort)0;
    }
    uint4 o;
    o.x = (unsigned)v[0] | ((unsigned)v[1] << 16);
    o.y = (unsigned)v[2] | ((unsigned)v[3] << 16);
    o.z = (unsigned)v[4] | ((unsigned)v[5] << 16);
    o.w = (unsigned)v[6] | ((unsigned)v[7] << 16);
    ((uint4*)dst)[idx] = o;
}

// CHW async DMAs: one K-chunk's CHW fragment tiles -> wave-private LDS buffer.
template<int CHW>
__device__ __forceinline__ void stage_chunk(const ushort* gp, ushort* dstbuf, int lane) {
#pragma unroll
    for (int mt = 0; mt < CHW; ++mt) {
        __builtin_amdgcn_global_load_lds(
            (const __attribute__((address_space(1))) void*)(gp + (size_t)mt * 512 + lane * 8),
            (__attribute__((address_space(3))) void*)(dstbuf + mt * 512),
            16, 0, 0);
    }
}

__device__ __forceinline__ void unpack4(const ushort* p, float (&o)[4]) {
    uint2 u = *(const uint2*)p;
    o[0] = bf2f((ushort)(u.x));  o[1] = bf2f((ushort)(u.x >> 16));
    o[2] = bf2f((ushort)(u.y));  o[3] = bf2f((ushort)(u.y >> 16));
}

// lane-local cell update (R0 body, CHW-templated; u = (S_w+mt)*4+q)
template<int CHW>
__device__ __forceinline__ void gate_phase(f32x4 (&acc)[2][CHW],
                                           float (&creg)[2][CHW],
                                           ushort* __restrict__ hbl,
                                           int lane, int S_w) {
    const int l15 = lane & 15, q = lane >> 4;
#pragma unroll
    for (int nt = 0; nt < 2; ++nt) {
#pragma unroll
        for (int mt = 0; mt < CHW; ++mt) {
            const int u = (S_w + mt) * 4 + q;
            const int n = nt * 16 + l15;
            f32x4 z = acc[nt][mt];
            float iv = sigmoid_fast(z[0]);
            float fv = sigmoid_fast(z[1]);
            float gv = tanh_fast(z[2]);
            float ov = sigmoid_fast(z[3]);
            float c = fv * creg[nt][mt] + iv * gv;
            creg[nt][mt] = c;
            hbl[n * HS + u] = f2bf(ov * tanh_fast(c));
        }
    }
}

// One run of slots [s0, s1): identical per-slot body to the verified R0 kernel
// (vmcnt(CHW) wait -> ds_read frags + bh -> 2*CHW MFMA -> lgkmcnt(0) -> restage).
template<int CHW>
__device__ __forceinline__ void run_slots(int s0, int s1, int t,
        ushort* __restrict__ sl, f32x4 (&acc)[2][CHW],
        const ushort* __restrict__ pk, const uint* gTab, const uint* bhTab,
        const ushort* hbflat, int bhbase, int lane, int& isl) {
#pragma unroll 1
    for (int s = s0; s < s1; ++s) {
        __builtin_amdgcn_s_waitcnt(0x0F70 | CHW);   // vmcnt(CHW): other buffer in flight
        ushort* buf = sl + ((t + s) & 1) * (CHW * 512);
        s16x8 frag[CHW];
#pragma unroll
        for (int mt = 0; mt < CHW; ++mt)
            frag[mt] = *(const s16x8*)(buf + mt * 512 + lane * 8);
        const ushort* bp = hbflat + bhTab[s] + bhbase;
        s16x8 bh0 = *(const s16x8*)bp;
        s16x8 bh1 = *(const s16x8*)(bp + 16 * HS);
#pragma unroll
        for (int mt = 0; mt < CHW; ++mt) {
            acc[0][mt] = __builtin_amdgcn_mfma_f32_16x16x32_bf16(frag[mt], bh0, acc[0][mt], 0, 0, 0);
            acc[1][mt] = __builtin_amdgcn_mfma_f32_16x16x32_bf16(frag[mt], bh1, acc[1][mt], 0, 0, 0);
        }
        __builtin_amdgcn_s_waitcnt(WAIT_LGKM0);  // WAR: frag reads done before restage
        stage_chunk<CHW>(pk + gTab[isl], buf, lane);
        isl = (isl == 34) ? 0 : isl + 1;
    }
}

// Full 100-step loop, templated on the wave's tile count. Both instantiations
// execute an identical barrier sequence (6/step), so divergent wave-uniform
// dispatch below is barrier-safe. INVARIANT (R1/R5/R9/R11): NO register arrays
// live across barriers anywhere in the kernel -- the allocator's budget is
// kernel-global, and any cross-barrier register state (loop OR epilogue)
// trips the 84-VGPR spill regime (+600-800 us of scratch traffic).
template<int CHW>
__device__ __forceinline__ void time_loop(const int S_w, const int lane,
        const int bhbase, ushort* __restrict__ sl, const ushort* __restrict__ pk,
        const uint* gTab, const uint* bhTab, ushort* __restrict__ hbflat,
        const ushort (&pbwb)[4][NP], const ushort (&xTs)[Tlen][BT]) {
    const int l15 = lane & 15, q = lane >> 4;

    float creg[3][2][CHW];
#pragma unroll
    for (int l = 0; l < 3; ++l)
#pragma unroll
        for (int nt = 0; nt < 2; ++nt)
#pragma unroll
            for (int mt = 0; mt < CHW; ++mt) creg[l][nt][mt] = 0.0f;

    // prologue: issue slots 0,1 (parities 0,1); steady 2*CHW DMAs in flight
    stage_chunk<CHW>(pk + gTab[0], sl, lane);
    stage_chunk<CHW>(pk + gTab[1], sl + CHW * 512, lane);
    int isl = 2;

    for (int t = 0; t < Tlen; ++t) {
        f32x4 acc[2][CHW];

        // ---- layer 0 acc init: b0 + W0^T x_t (bf16 LDS constants) ----
        const float xn0 = bf2f(xTs[t][l15]);
        const float xn1 = bf2f(xTs[t][16 + l15]);
#pragma unroll
        for (int mt = 0; mt < CHW; ++mt) {
            const int row = (S_w + mt) * 16 + q * 4;
            float bb[4], ww[4];
            unpack4(&pbwb[0][row], bb);
            unpack4(&pbwb[3][row], ww);
#pragma unroll
            for (int r = 0; r < 4; ++r) {
                acc[0][mt][r] = fmaf(xn0, ww[r], bb[r]);
                acc[1][mt][r] = fmaf(xn1, ww[r], bb[r]);
            }
        }

        // ---- region A: slots 0..6 (U0 x h0_old) ----
        run_slots<CHW>(0, 7, t, sl, acc, pk, gTab, bhTab, hbflat, bhbase, lane, isl);
        wg_barrier();
        gate_phase<CHW>(acc, creg[0], hbflat + 0 * BT * HS, lane, S_w);
        wg_barrier();

        // ---- layer 1 acc init ----
#pragma unroll
        for (int mt = 0; mt < CHW; ++mt) {
            const int row = (S_w + mt) * 16 + q * 4;
            float bb[4];
            unpack4(&pbwb[1][row], bb);
#pragma unroll
            for (int r = 0; r < 4; ++r) { acc[0][mt][r] = bb[r]; acc[1][mt][r] = bb[r]; }
        }
        // ---- region B: slots 7..20 (U1 x h1_old, W1 x h0_new, rotated mix) ----
        run_slots<CHW>(7, 21, t, sl, acc, pk, gTab, bhTab, hbflat, bhbase, lane, isl);
        wg_barrier();
        gate_phase<CHW>(acc, creg[1], hbflat + 1 * BT * HS, lane, S_w);
        wg_barrier();

        // ---- layer 2 acc init ----
#pragma unroll
        for (int mt = 0; mt < CHW; ++mt) {
            const int row = (S_w + mt) * 16 + q * 4;
            float bb[4];
            unpack4(&pbwb[2][row], bb);
#pragma unroll
            for (int r = 0; r < 4; ++r) { acc[0][mt][r] = bb[r]; acc[1][mt][r] = bb[r]; }
        }
        // ---- region C: slots 21..34 (U2 x h2_old, W2 x h1_new, rotated mix) ----
        run_slots<CHW>(21, 35, t, sl, acc, pk, gTab, bhTab, hbflat, bhbase, lane, isl);
        wg_barrier();
        gate_phase<CHW>(acc, creg[2], hbflat + 2 * BT * HS, lane, S_w);
        wg_barrier();
    }
}

__global__ void __launch_bounds__(THREADS)
lstm3_mfma(const float* __restrict__ x,
           const float* __restrict__ W0, const float* __restrict__ b0,
           const float* __restrict__ b1, const float* __restrict__ b2,
           const float* __restrict__ Wfc, const float* __restrict__ bfc,
           const ushort* __restrict__ packed,
           float* __restrict__ out) {
    __shared__ ushort hb[3][BT][HS];        // h state, bf16 (44.5 KB)
    __shared__ ushort stage[NT * 1024];     // per-wave 2-deep staging, packed (100 KB)
    __shared__ ushort pbwb[4][NP];          // permuted b0,b1,b2,W0 as bf16 (6.4 KB)
    __shared__ ushort xTs[Tlen][BT];        // x transposed, bf16 (6.4 KB)
    __shared__ uint   gTab[35];             // rotated weight-chunk offsets (ushorts)
    __shared__ uint   bhTab[35];            // matching h-operand offsets (ushorts)

    const int tid = threadIdx.x;
    const int wave = tid >> 6, lane = tid & 63;
    const int bx = blockIdx.x;
    const int bbase = bx * BT;

    for (int i = tid; i < 3 * BT * HS; i += THREADS) ((ushort*)hb)[i] = 0;
    for (int i = tid; i < NP; i += THREADS) {
        int nc = (i & 3) * Hdim + (i >> 2);   // permuted col -> src col
        pbwb[0][i] = f2bf(b0[nc]); pbwb[1][i] = f2bf(b1[nc]);
        pbwb[2][i] = f2bf(b2[nc]); pbwb[3][i] = f2bf(W0[nc]);
    }
    for (int i = tid; i < BT * Tlen; i += THREADS) {
        int m = i / Tlen, tt = i % Tlen;
        xTs[tt][m] = f2bf(x[(size_t)(bbase + m) * Tlen + tt]);
    }
    // per-WG rotated chunk tables: slot s in [0,35) -> weight offset + h offset
    // (identical to the verified R0 tables)
    if (tid < 35) {
        int s = tid; uint goff, bhoff;
        if (s < 7) {                       // layer0: U0, B=h0
            int c = (s + bx) % 7;
            goff = 0u * MATSZ + c * CHSTR;           bhoff = 0u * BT * HS + c * 32;
        } else if (s < 21) {               // layer1: U1 (B=h1) then W1 (B=h0new), rotated
            int c = (s - 7 + bx) % 14;
            if (c < 7) { goff = 2u * MATSZ + c * CHSTR;       bhoff = 1u * BT * HS + c * 32; }
            else       { goff = 1u * MATSZ + (c - 7) * CHSTR; bhoff = 0u * BT * HS + (c - 7) * 32; }
        } else {                           // layer2: U2 (B=h2) then W2 (B=h1new), rotated
            int c = (s - 21 + bx * 5) % 14;
            if (c < 7) { goff = 4u * MATSZ + c * CHSTR;       bhoff = 2u * BT * HS + c * 32; }
            else       { goff = 3u * MATSZ + (c - 7) * CHSTR; bhoff = 1u * BT * HS + (c - 7) * 32; }
        }
        gTab[s] = goff; bhTab[s] = bhoff;
    }
    __syncthreads();

    // Tile split: waves 0,1 own 5 tiles; waves 2..11 own 4 (total 50).
    // Round-robin wave->SIMD puts the 5-tile waves on SIMD0/SIMD1:
    // per-SIMD tiles {13,13,12,12} -> 4% imbalance (vs 640-thread 15/10 = 20%).
    const int S_w = (wave < 2) ? wave * 5 : 10 + (wave - 2) * 4;
    const ushort* pk = packed + (size_t)S_w * 512;   // wave's first tile
    ushort* sl = &stage[S_w * 1024];                 // 2 x CHW x 512 ushorts
    ushort* hbflat = &hb[0][0][0];
    const int bhbase = (lane & 15) * HS + (lane >> 4) * 8;

    if (wave < 2) time_loop<5>(S_w, lane, bhbase, sl, pk, gTab, bhTab, hbflat, pbwb, xTs);
    else          time_loop<4>(S_w, lane, bhbase, sl, pk, gTab, bhTab, hbflat, pbwb, xTs);

    __syncthreads();   // full drain (absorbs wrap DMAs) + h2 visibility

    // ---- dense head: y = tanh(h2 @ Wfc + bfc) ----
    // Untiled (L2-fed) on purpose: the LDS-tiled variant requires accumulators
    // live across staging barriers, which trips the kernel-global spill regime
    // (R11: +800 us). The ~60 us L2 re-read tail is the cheaper price.
    for (int gidx = tid; gidx < BT * 100; gidx += THREADS) {
        int m = gidx / 100;
        int j4 = (gidx % 100) * 4;
        const ushort* h2 = &hb[2][m][0];
        float4 a4 = *(const float4*)(bfc + j4);
        float s0 = a4.x, s1 = a4.y, s2 = a4.z, s3 = a4.w;
        for (int k = 0; k < Hdim; ++k) {
            float hk = bf2f(h2[k]);
            float4 w4 = *(const float4*)(Wfc + (size_t)k * 400 + j4);
            s0 = fmaf(hk, w4.x, s0);
            s1 = fmaf(hk, w4.y, s1);
            s2 = fmaf(hk, w4.z, s2);
            s3 = fmaf(hk, w4.w, s3);
        }
        float4 o4;
        o4.x = tanh_fast(s0); o4.y = tanh_fast(s1);
        o4.z = tanh_fast(s2); o4.w = tanh_fast(s3);
        *(float4*)(out + (size_t)(bbase + m) * 400 + j4) = o4;
    }
}

extern "C" void kernel_launch(void* const* d_in, const int* in_sizes, int n_in,
                              void* d_out, int out_size, void* d_ws, size_t ws_size,
                              hipStream_t stream) {
    const float* x   = (const float*)d_in[0];
    const float* W0  = (const float*)d_in[1];
    const float* U0  = (const float*)d_in[2];
    const float* b0  = (const float*)d_in[3];
    const float* W1  = (const float*)d_in[4];
    const float* U1  = (const float*)d_in[5];
    const float* b1  = (const float*)d_in[6];
    const float* W2  = (const float*)d_in[7];
    const float* U2  = (const float*)d_in[8];
    const float* b2  = (const float*)d_in[9];
    const float* Wfc = (const float*)d_in[10];
    const float* bfc = (const float*)d_in[11];
    float* out = (float*)d_out;
    ushort* packed = (ushort*)d_ws;

    const int B = in_sizes[0] / Tlen;   // 8192
    const int pack_threads = 5 * KB * NT * 64;
    pack_weights<<<(pack_threads + 255) / 256, 256, 0, stream>>>(U0, W1, U1, W2, U2, packed);
    lstm3_mfma<<<B / BT, THREADS, 0, stream>>>(x, W0, b0, b1, b2, Wfc, bfc, packed, out);
}